// Round 3
// baseline (559.019 us; speedup 1.0000x reference)
//
#include <hip/hip_runtime.h>
#include <hip/hip_cooperative_groups.h>
#include <math.h>

namespace cg = cooperative_groups;

#define DIM 4096
#define INTER 11008
#define EPS 1e-5f
#define THRESH 0.05f

typedef float f4 __attribute__((ext_vector_type(4)));

__device__ __forceinline__ f4 ntload(const float* p) {
    return __builtin_nontemporal_load(reinterpret_cast<const f4*>(p));
}
__device__ __forceinline__ f4 ld4(const float* p) {
    return *reinterpret_cast<const f4*>(p);
}

__device__ __forceinline__ float wave_sum(float v) {
#pragma unroll
    for (int off = 32; off > 0; off >>= 1) v += __shfl_xor(v, off, 64);
    return v;
}

__device__ __forceinline__ float thr(float v) {
    return (fabsf(v) > THRESH) ? v : 0.f;
}

// Per-wave RMS scale of a DIM-length vector (redundant per wave; vector is
// L2-resident, cost hidden under HBM weight streaming).
__device__ __forceinline__ float wave_rms_scale(const float* __restrict__ x,
                                                int lane) {
    float ss = 0.f;
#pragma unroll
    for (int k = 0; k < DIM; k += 256) {
        f4 v = ld4(x + k + (lane << 2));
        ss = fmaf(v.x, v.x, ss);
        ss = fmaf(v.y, v.y, ss);
        ss = fmaf(v.z, v.z, ss);
        ss = fmaf(v.w, v.w, ss);
    }
    ss = wave_sum(ss);
    return rsqrtf(ss * (1.f / (float)DIM) + EPS);
}

// dot(W[row], thr(x*scale*nw)) over K=DIM; weights streamed nontemporally.
__device__ __forceinline__ float dot_row_norm(const float* __restrict__ wr,
        const float* __restrict__ x, const float* __restrict__ nw,
        float scale, int lane) {
    float acc[4] = {0.f, 0.f, 0.f, 0.f};
    for (int k = 0; k < DIM; k += 1024) {
#pragma unroll
        for (int u = 0; u < 4; ++u) {
            const int kk = k + (u << 8) + (lane << 2);
            f4 wv = ntload(wr + kk);
            f4 xv = ld4(x + kk);
            f4 nv = ld4(nw + kk);
            float x0 = thr(xv.x * scale * nv.x);
            float x1 = thr(xv.y * scale * nv.y);
            float x2 = thr(xv.z * scale * nv.z);
            float x3 = thr(xv.w * scale * nv.w);
            acc[u] = fmaf(wv.x, x0, acc[u]);
            acc[u] = fmaf(wv.y, x1, acc[u]);
            acc[u] = fmaf(wv.z, x2, acc[u]);
            acc[u] = fmaf(wv.w, x3, acc[u]);
        }
    }
    return wave_sum((acc[0] + acc[1]) + (acc[2] + acc[3]));
}

// plain dot(W[row], x) over K=DIM
__device__ __forceinline__ float dot_row(const float* __restrict__ wr,
        const float* __restrict__ x, int lane) {
    float acc[4] = {0.f, 0.f, 0.f, 0.f};
    for (int k = 0; k < DIM; k += 1024) {
#pragma unroll
        for (int u = 0; u < 4; ++u) {
            const int kk = k + (u << 8) + (lane << 2);
            f4 wv = ntload(wr + kk);
            f4 xv = ld4(x + kk);
            acc[u] = fmaf(wv.x, xv.x, acc[u]);
            acc[u] = fmaf(wv.y, xv.y, acc[u]);
            acc[u] = fmaf(wv.z, xv.z, acc[u]);
            acc[u] = fmaf(wv.w, xv.w, acc[u]);
        }
    }
    return wave_sum((acc[0] + acc[1]) + (acc[2] + acc[3]));
}

// simultaneous dots of w1[row],w3[row] against normalized h
__device__ __forceinline__ void dot2_row_norm(const float* __restrict__ w1r,
        const float* __restrict__ w3r, const float* __restrict__ h,
        const float* __restrict__ nw, float scale, int lane,
        float& g_out, float& u_out) {
    float g[2] = {0.f, 0.f}, u[2] = {0.f, 0.f};
    for (int k = 0; k < DIM; k += 512) {
#pragma unroll
        for (int p = 0; p < 2; ++p) {
            const int kk = k + (p << 8) + (lane << 2);
            f4 hv = ld4(h + kk);
            f4 nv = ld4(nw + kk);
            f4 av = ntload(w1r + kk);
            f4 bv = ntload(w3r + kk);
            float x0 = thr(hv.x * scale * nv.x);
            float x1 = thr(hv.y * scale * nv.y);
            float x2 = thr(hv.z * scale * nv.z);
            float x3 = thr(hv.w * scale * nv.w);
            g[p] = fmaf(av.x, x0, g[p]);
            g[p] = fmaf(av.y, x1, g[p]);
            g[p] = fmaf(av.z, x2, g[p]);
            g[p] = fmaf(av.w, x3, g[p]);
            u[p] = fmaf(bv.x, x0, u[p]);
            u[p] = fmaf(bv.y, x1, u[p]);
            u[p] = fmaf(bv.z, x2, u[p]);
            u[p] = fmaf(bv.w, x3, u[p]);
        }
    }
    g_out = wave_sum(g[0] + g[1]);
    u_out = wave_sum(u[0] + u[1]);
}

// dot(W2[row], x) over K=INTER
__device__ __forceinline__ float dot_row_inter(const float* __restrict__ wr,
        const float* __restrict__ x, int lane) {
    float acc[4] = {0.f, 0.f, 0.f, 0.f};
    int k = 0;
    for (; k + 1024 <= INTER; k += 1024) {
#pragma unroll
        for (int u = 0; u < 4; ++u) {
            const int kk = k + (u << 8) + (lane << 2);
            f4 wv = ntload(wr + kk);
            f4 xv = ld4(x + kk);
            acc[u] = fmaf(wv.x, xv.x, acc[u]);
            acc[u] = fmaf(wv.y, xv.y, acc[u]);
            acc[u] = fmaf(wv.z, xv.z, acc[u]);
            acc[u] = fmaf(wv.w, xv.w, acc[u]);
        }
    }
#pragma unroll
    for (int u = 0; u < 3; ++u) {  // tail 768
        const int kk = k + (u << 8) + (lane << 2);
        f4 wv = ntload(wr + kk);
        f4 xv = ld4(x + kk);
        acc[u] = fmaf(wv.x, xv.x, acc[u]);
        acc[u] = fmaf(wv.y, xv.y, acc[u]);
        acc[u] = fmaf(wv.z, xv.z, acc[u]);
        acc[u] = fmaf(wv.w, xv.w, acc[u]);
    }
    return wave_sum((acc[0] + acc[1]) + (acc[2] + acc[3]));
}

__device__ __forceinline__ float silu_mul_thr(float g, float u) {
    float s = g / (1.f + expf(-g));
    return thr(s * u);
}

// ---------------- fused cooperative kernel ----------------
// 1024 blocks x 256 threads = 4096 waves, 4 blocks/CU (co-resident).
__global__ __launch_bounds__(256, 4) void fused_layer_kernel(
        const float* __restrict__ x, const float* __restrict__ wv,
        const float* __restrict__ wo, const float* __restrict__ w1,
        const float* __restrict__ w2, const float* __restrict__ w3,
        const float* __restrict__ anw, const float* __restrict__ fnw,
        float* __restrict__ vt, float* __restrict__ h,
        float* __restrict__ actt, float* __restrict__ out) {
    cg::grid_group grid = cg::this_grid();
    const int lane = threadIdx.x & 63;
    const int wid = (blockIdx.x << 2) + (threadIdx.x >> 6);  // 0..4095

    // Phase 1: vt = thr(wv · thr(rmsnorm(x)*anw))   (SEQ=1: attn out == V)
    {
        const float scale = wave_rms_scale(x, lane);
        float a = dot_row_norm(wv + (size_t)wid * DIM, x, anw, scale, lane);
        if (lane == 0) vt[wid] = thr(a);
    }
    grid.sync();

    // Phase 2: h = x + wo · vt
    {
        float a = dot_row(wo + (size_t)wid * DIM, vt, lane);
        if (lane == 0) h[wid] = x[wid] + a;
    }
    grid.sync();

    // Phase 3: actt[r] = thr(silu(w1·hn) * (w3·hn)), rows wid, wid+4096, wid+8192
    {
        const float scale = wave_rms_scale(h, lane);
        for (int r = wid; r < INTER; r += 4096) {
            float g, u;
            dot2_row_norm(w1 + (size_t)r * DIM, w3 + (size_t)r * DIM,
                          h, fnw, scale, lane, g, u);
            if (lane == 0) actt[r] = silu_mul_thr(g, u);
        }
    }
    grid.sync();

    // Phase 4: out = h + w2 · actt
    {
        float a = dot_row_inter(w2 + (size_t)wid * INTER, actt, lane);
        if (lane == 0) out[wid] = h[wid] + a;
    }
}

// ---------------- fallback kernels (if cooperative launch unsupported) ----
__global__ __launch_bounds__(256) void k_v(const float* __restrict__ wv,
        const float* __restrict__ x, const float* __restrict__ anw,
        float* __restrict__ vt) {
    const int lane = threadIdx.x & 63;
    const int wid = (blockIdx.x << 2) + (threadIdx.x >> 6);
    const float scale = wave_rms_scale(x, lane);
    float a = dot_row_norm(wv + (size_t)wid * DIM, x, anw, scale, lane);
    if (lane == 0) vt[wid] = thr(a);
}
__global__ __launch_bounds__(256) void k_o(const float* __restrict__ wo,
        const float* __restrict__ vt, const float* __restrict__ x,
        float* __restrict__ h) {
    const int lane = threadIdx.x & 63;
    const int wid = (blockIdx.x << 2) + (threadIdx.x >> 6);
    float a = dot_row(wo + (size_t)wid * DIM, vt, lane);
    if (lane == 0) h[wid] = x[wid] + a;
}
__global__ __launch_bounds__(256) void k_gu(const float* __restrict__ w1,
        const float* __restrict__ w3, const float* __restrict__ h,
        const float* __restrict__ fnw, float* __restrict__ actt) {
    const int lane = threadIdx.x & 63;
    const int wid = (blockIdx.x << 2) + (threadIdx.x >> 6);
    const float scale = wave_rms_scale(h, lane);
    float g, u;
    dot2_row_norm(w1 + (size_t)wid * DIM, w3 + (size_t)wid * DIM,
                  h, fnw, scale, lane, g, u);
    if (lane == 0) actt[wid] = silu_mul_thr(g, u);
}
__global__ __launch_bounds__(256) void k_d(const float* __restrict__ w2,
        const float* __restrict__ actt, const float* __restrict__ h,
        float* __restrict__ out) {
    const int lane = threadIdx.x & 63;
    const int wid = (blockIdx.x << 2) + (threadIdx.x >> 6);
    float a = dot_row_inter(w2 + (size_t)wid * INTER, actt, lane);
    if (lane == 0) out[wid] = h[wid] + a;
}

extern "C" void kernel_launch(void* const* d_in, const int* in_sizes, int n_in,
                              void* d_out, int out_size, void* d_ws, size_t ws_size,
                              hipStream_t stream) {
    // setup_inputs order: x, freqs_cis, wqkv, wo, w1, w2, w3, attn_norm_w, ffn_norm_w, mask
    const float* x    = (const float*)d_in[0];
    const float* wqkv = (const float*)d_in[2];
    const float* wo   = (const float*)d_in[3];
    const float* w1   = (const float*)d_in[4];
    const float* w2   = (const float*)d_in[5];
    const float* w3   = (const float*)d_in[6];
    const float* anw  = (const float*)d_in[7];
    const float* fnw  = (const float*)d_in[8];
    float* out = (float*)d_out;

    float* ws   = (float*)d_ws;
    float* vt   = ws;            // 4096
    float* h    = ws + 4096;     // 4096
    float* actt = ws + 8192;     // 11008

    // V block of wqkv; Q/K rows are dead at SEQ=1 (softmax over 1 key == 1,
    // RoPE at pos 0 is identity).
    const float* wv = wqkv + (size_t)2 * 4096 * DIM;

    void* args[] = {(void*)&x, (void*)&wv, (void*)&wo, (void*)&w1,
                    (void*)&w2, (void*)&w3, (void*)&anw, (void*)&fnw,
                    (void*)&vt, (void*)&h, (void*)&actt, (void*)&out};
    hipError_t err = hipLaunchCooperativeKernel(
        (const void*)fused_layer_kernel, dim3(1024), dim3(256), args, 0, stream);
    if (err != hipSuccess) {
        // fallback: 4-kernel chain
        k_v <<<DIM / 4, 256, 0, stream>>>(wv, x, anw, vt);
        k_o <<<DIM / 4, 256, 0, stream>>>(wo, vt, x, h);
        k_gu<<<INTER / 4, 256, 0, stream>>>(w1, w3, h, fnw, actt);
        k_d <<<DIM / 4, 256, 0, stream>>>(w2, actt, h, out);
    }
}

// Round 4
// 138.785 us; speedup vs baseline: 4.0280x; 4.0280x over previous
//
#include <hip/hip_runtime.h>
#include <math.h>

#define DIM 4096
#define INTER 11008
#define EPS 1e-5f
#define THRESH 0.05f

typedef float f4 __attribute__((ext_vector_type(4)));

__device__ __forceinline__ f4 ld4(const float* p) {
    return *reinterpret_cast<const f4*>(p);
}

__device__ __forceinline__ float wave_sum(float v) {
#pragma unroll
    for (int off = 32; off > 0; off >>= 1) v += __shfl_xor(v, off, 64);
    return v;
}

__device__ __forceinline__ float thr(float v) {
    return (fabsf(v) > THRESH) ? v : 0.f;
}

// Per-wave RMS scale of a DIM-length vector (redundant per wave; the vector
// is L2-resident so this hides under the HBM weight streaming).
__device__ __forceinline__ float wave_rms_scale(const float* __restrict__ x,
                                                int lane) {
    float ss = 0.f;
#pragma unroll
    for (int k = 0; k < DIM; k += 256) {
        f4 v = ld4(x + k + (lane << 2));
        ss = fmaf(v.x, v.x, ss);
        ss = fmaf(v.y, v.y, ss);
        ss = fmaf(v.z, v.z, ss);
        ss = fmaf(v.w, v.w, ss);
    }
    ss = wave_sum(ss);
    return rsqrtf(ss * (1.f / (float)DIM) + EPS);
}

// ---- two-row dot products (one wave owns rows r0, r1 = adjacent) ----

// acc0/acc1 = dot(W[r0/r1], thr(x*scale*nw)) over K=DIM
__device__ __forceinline__ void dot2_norm(const float* __restrict__ wr0,
        const float* __restrict__ wr1, const float* __restrict__ x,
        const float* __restrict__ nw, float scale, int lane,
        float& o0, float& o1) {
    float a0 = 0.f, a1 = 0.f;
#pragma unroll 2
    for (int k = 0; k < DIM; k += 256) {
        const int kk = k + (lane << 2);
        f4 xv = ld4(x + kk);
        f4 nv = ld4(nw + kk);
        f4 w0 = ld4(wr0 + kk);
        f4 w1 = ld4(wr1 + kk);
        float x0 = thr(xv.x * scale * nv.x);
        float x1 = thr(xv.y * scale * nv.y);
        float x2 = thr(xv.z * scale * nv.z);
        float x3 = thr(xv.w * scale * nv.w);
        a0 = fmaf(w0.x, x0, a0); a0 = fmaf(w0.y, x1, a0);
        a0 = fmaf(w0.z, x2, a0); a0 = fmaf(w0.w, x3, a0);
        a1 = fmaf(w1.x, x0, a1); a1 = fmaf(w1.y, x1, a1);
        a1 = fmaf(w1.z, x2, a1); a1 = fmaf(w1.w, x3, a1);
    }
    o0 = wave_sum(a0);
    o1 = wave_sum(a1);
}

// plain two-row dot over compile-time K (256 | K)
template <int K>
__device__ __forceinline__ void dot2(const float* __restrict__ wr0,
        const float* __restrict__ wr1, const float* __restrict__ x,
        int lane, float& o0, float& o1) {
    float a0 = 0.f, a1 = 0.f;
#pragma unroll 2
    for (int k = 0; k < K; k += 256) {
        const int kk = k + (lane << 2);
        f4 xv = ld4(x + kk);
        f4 w0 = ld4(wr0 + kk);
        f4 w1 = ld4(wr1 + kk);
        a0 = fmaf(w0.x, xv.x, a0); a0 = fmaf(w0.y, xv.y, a0);
        a0 = fmaf(w0.z, xv.z, a0); a0 = fmaf(w0.w, xv.w, a0);
        a1 = fmaf(w1.x, xv.x, a1); a1 = fmaf(w1.y, xv.y, a1);
        a1 = fmaf(w1.z, xv.z, a1); a1 = fmaf(w1.w, xv.w, a1);
    }
    o0 = wave_sum(a0);
    o1 = wave_sum(a1);
}

// four dots (w1/w3 x two rows) against normalized h
__device__ __forceinline__ void dot4_norm(const float* __restrict__ g0p,
        const float* __restrict__ g1p, const float* __restrict__ u0p,
        const float* __restrict__ u1p, const float* __restrict__ h,
        const float* __restrict__ nw, float scale, int lane,
        float& g0, float& g1, float& u0, float& u1) {
    float ag0 = 0.f, ag1 = 0.f, au0 = 0.f, au1 = 0.f;
#pragma unroll 2
    for (int k = 0; k < DIM; k += 256) {
        const int kk = k + (lane << 2);
        f4 hv = ld4(h + kk);
        f4 nv = ld4(nw + kk);
        f4 a0 = ld4(g0p + kk);
        f4 a1 = ld4(g1p + kk);
        f4 b0 = ld4(u0p + kk);
        f4 b1 = ld4(u1p + kk);
        float x0 = thr(hv.x * scale * nv.x);
        float x1 = thr(hv.y * scale * nv.y);
        float x2 = thr(hv.z * scale * nv.z);
        float x3 = thr(hv.w * scale * nv.w);
        ag0 = fmaf(a0.x, x0, ag0); ag0 = fmaf(a0.y, x1, ag0);
        ag0 = fmaf(a0.z, x2, ag0); ag0 = fmaf(a0.w, x3, ag0);
        ag1 = fmaf(a1.x, x0, ag1); ag1 = fmaf(a1.y, x1, ag1);
        ag1 = fmaf(a1.z, x2, ag1); ag1 = fmaf(a1.w, x3, ag1);
        au0 = fmaf(b0.x, x0, au0); au0 = fmaf(b0.y, x1, au0);
        au0 = fmaf(b0.z, x2, au0); au0 = fmaf(b0.w, x3, au0);
        au1 = fmaf(b1.x, x0, au1); au1 = fmaf(b1.y, x1, au1);
        au1 = fmaf(b1.z, x2, au1); au1 = fmaf(b1.w, x3, au1);
    }
    g0 = wave_sum(ag0);
    g1 = wave_sum(ag1);
    u0 = wave_sum(au0);
    u1 = wave_sum(au1);
}

__device__ __forceinline__ float silu_mul_thr(float g, float u) {
    float s = g / (1.f + expf(-g));
    return thr(s * u);
}

// ---------------- kernels (2 rows per wave, 4 waves/block) ----------------

// vt[r] = thr( wv[r]·thr(rmsnorm(x)*anw) ), r = 2 rows/wave. SEQ=1: attn out == V.
__global__ __launch_bounds__(256) void k_v(const float* __restrict__ wv,
        const float* __restrict__ x, const float* __restrict__ anw,
        float* __restrict__ vt) {
    const int lane = threadIdx.x & 63;
    const int wid = (blockIdx.x << 2) + (threadIdx.x >> 6);
    const int r0 = wid << 1;
    const float scale = wave_rms_scale(x, lane);
    float o0, o1;
    dot2_norm(wv + (size_t)r0 * DIM, wv + (size_t)(r0 + 1) * DIM,
              x, anw, scale, lane, o0, o1);
    if (lane == 0) {
        vt[r0] = thr(o0);
        vt[r0 + 1] = thr(o1);
    }
}

// h[r] = x[r] + wo[r]·vt
__global__ __launch_bounds__(256) void k_o(const float* __restrict__ wo,
        const float* __restrict__ vt, const float* __restrict__ x,
        float* __restrict__ h) {
    const int lane = threadIdx.x & 63;
    const int wid = (blockIdx.x << 2) + (threadIdx.x >> 6);
    const int r0 = wid << 1;
    float o0, o1;
    dot2<DIM>(wo + (size_t)r0 * DIM, wo + (size_t)(r0 + 1) * DIM,
              vt, lane, o0, o1);
    if (lane == 0) {
        h[r0] = x[r0] + o0;
        h[r0 + 1] = x[r0 + 1] + o1;
    }
}

// actt[r] = thr( silu(w1[r]·hn) * (w3[r]·hn) ), hn = thr(rmsnorm(h)*fnw)
__global__ __launch_bounds__(256) void k_gu(const float* __restrict__ w1,
        const float* __restrict__ w3, const float* __restrict__ h,
        const float* __restrict__ fnw, float* __restrict__ actt) {
    const int lane = threadIdx.x & 63;
    const int wid = (blockIdx.x << 2) + (threadIdx.x >> 6);
    const int r0 = wid << 1;
    const float scale = wave_rms_scale(h, lane);
    float g0, g1, u0, u1;
    dot4_norm(w1 + (size_t)r0 * DIM, w1 + (size_t)(r0 + 1) * DIM,
              w3 + (size_t)r0 * DIM, w3 + (size_t)(r0 + 1) * DIM,
              h, fnw, scale, lane, g0, g1, u0, u1);
    if (lane == 0) {
        actt[r0] = silu_mul_thr(g0, u0);
        actt[r0 + 1] = silu_mul_thr(g1, u1);
    }
}

// out[r] = h[r] + w2[r]·actt  (K = INTER = 43*256)
__global__ __launch_bounds__(256) void k_d(const float* __restrict__ w2,
        const float* __restrict__ actt, const float* __restrict__ h,
        float* __restrict__ out) {
    const int lane = threadIdx.x & 63;
    const int wid = (blockIdx.x << 2) + (threadIdx.x >> 6);
    const int r0 = wid << 1;
    float o0, o1;
    dot2<INTER>(w2 + (size_t)r0 * INTER, w2 + (size_t)(r0 + 1) * INTER,
                actt, lane, o0, o1);
    if (lane == 0) {
        out[r0] = h[r0] + o0;
        out[r0 + 1] = h[r0 + 1] + o1;
    }
}

extern "C" void kernel_launch(void* const* d_in, const int* in_sizes, int n_in,
                              void* d_out, int out_size, void* d_ws, size_t ws_size,
                              hipStream_t stream) {
    // setup_inputs order: x, freqs_cis, wqkv, wo, w1, w2, w3, attn_norm_w, ffn_norm_w, mask
    const float* x    = (const float*)d_in[0];
    const float* wqkv = (const float*)d_in[2];
    const float* wo   = (const float*)d_in[3];
    const float* w1   = (const float*)d_in[4];
    const float* w2   = (const float*)d_in[5];
    const float* w3   = (const float*)d_in[6];
    const float* anw  = (const float*)d_in[7];
    const float* fnw  = (const float*)d_in[8];
    float* out = (float*)d_out;

    float* ws   = (float*)d_ws;
    float* vt   = ws;            // 4096
    float* h    = ws + 4096;     // 4096
    float* actt = ws + 8192;     // 11008

    // V block of wqkv; Q/K rows are dead at SEQ=1 (softmax over 1 key == 1,
    // RoPE at pos 0 is identity).
    const float* wv = wqkv + (size_t)2 * 4096 * DIM;

    k_v <<<DIM / 8, 256, 0, stream>>>(wv, x, anw, vt);          // 512 blocks
    k_o <<<DIM / 8, 256, 0, stream>>>(wo, vt, x, h);            // 512 blocks
    k_gu<<<INTER / 8, 256, 0, stream>>>(w1, w3, h, fnw, actt);  // 1376 blocks
    k_d <<<DIM / 8, 256, 0, stream>>>(w2, actt, h, out);        // 512 blocks
}

// Round 5
// 136.502 us; speedup vs baseline: 4.0953x; 1.0167x over previous
//
#include <hip/hip_runtime.h>
#include <math.h>

#define DIM 4096
#define INTER 11008
#define EPS 1e-5f
#define THRESH 0.05f

typedef float f4 __attribute__((ext_vector_type(4)));

__device__ __forceinline__ f4 ld4(const float* p) {
    return *reinterpret_cast<const f4*>(p);
}

__device__ __forceinline__ float wave_sum(float v) {
#pragma unroll
    for (int off = 32; off > 0; off >>= 1) v += __shfl_xor(v, off, 64);
    return v;
}

__device__ __forceinline__ float thr(float v) {
    return (fabsf(v) > THRESH) ? v : 0.f;
}

__device__ __forceinline__ float dot4(f4 a, f4 b, float acc) {
    acc = fmaf(a.x, b.x, acc);
    acc = fmaf(a.y, b.y, acc);
    acc = fmaf(a.z, b.z, acc);
    acc = fmaf(a.w, b.w, acc);
    return acc;
}

__device__ __forceinline__ f4 norm_thr(f4 x, f4 n, float scale) {
    f4 o;
    o.x = thr(x.x * scale * n.x);
    o.y = thr(x.y * scale * n.y);
    o.z = thr(x.z * scale * n.z);
    o.w = thr(x.w * scale * n.w);
    return o;
}

// ---------------------------------------------------------------------------
// k_v: vt[r] = thr( Wv[r] · thr(rmsnorm(x)*anw) )
// 2 rows/block, each row split across 2 waves (8KB contiguous half-rows).
// 32 waves/CU; 8 weight loads fully unrolled per wave.
__global__ __launch_bounds__(256) void k_v(const float* __restrict__ Wv,
        const float* __restrict__ x, const float* __restrict__ anw,
        float* __restrict__ vt) {
    __shared__ float red_ss[4];
    __shared__ float red_dot[4];
    const int tid = threadIdx.x;
    const int lane = tid & 63;
    const int w = tid >> 6;            // 0..3
    const int rowsel = w >> 1;         // 0..1
    const int half = w & 1;            // 0..1
    const int r0 = blockIdx.x << 1;
    const int r = r0 + rowsel;
    const int base = (half << 11) + (lane << 2);  // half*2048 + lane*4

    // load x half into regs + partial sum of squares
    f4 xv[8];
    float ss[4] = {0.f, 0.f, 0.f, 0.f};
#pragma unroll
    for (int i = 0; i < 8; ++i) {
        xv[i] = ld4(x + base + (i << 8));
        ss[i & 3] = dot4(xv[i], xv[i], ss[i & 3]);
    }
    float s = wave_sum((ss[0] + ss[1]) + (ss[2] + ss[3]));
    if (lane == 0) red_ss[w] = s;
    __syncthreads();
    const float scale = rsqrtf((red_ss[0] + red_ss[1]) * (1.f / (float)DIM) + EPS);

    // normalize + threshold in regs
#pragma unroll
    for (int i = 0; i < 8; ++i)
        xv[i] = norm_thr(xv[i], ld4(anw + base + (i << 8)), scale);

    // stream the weight half-row: 8 independent loads
    const float* wr = Wv + (size_t)r * DIM;
    float acc[4] = {0.f, 0.f, 0.f, 0.f};
#pragma unroll
    for (int i = 0; i < 8; ++i)
        acc[i & 3] = dot4(ld4(wr + base + (i << 8)), xv[i], acc[i & 3]);
    float a = wave_sum((acc[0] + acc[1]) + (acc[2] + acc[3]));
    if (lane == 0) red_dot[w] = a;
    __syncthreads();
    if (tid == 0) {
        vt[r0]     = thr(red_dot[0] + red_dot[1]);
        vt[r0 + 1] = thr(red_dot[2] + red_dot[3]);
    }
}

// ---------------------------------------------------------------------------
// k_o: h[r] = x[r] + Wo[r] · vt   (same split-k x2 layout)
__global__ __launch_bounds__(256) void k_o(const float* __restrict__ Wo,
        const float* __restrict__ vt, const float* __restrict__ x,
        float* __restrict__ h) {
    __shared__ float red_dot[4];
    const int tid = threadIdx.x;
    const int lane = tid & 63;
    const int w = tid >> 6;
    const int rowsel = w >> 1;
    const int half = w & 1;
    const int r0 = blockIdx.x << 1;
    const int r = r0 + rowsel;
    const int base = (half << 11) + (lane << 2);

    f4 av[8];
#pragma unroll
    for (int i = 0; i < 8; ++i) av[i] = ld4(vt + base + (i << 8));

    const float* wr = Wo + (size_t)r * DIM;
    float acc[4] = {0.f, 0.f, 0.f, 0.f};
#pragma unroll
    for (int i = 0; i < 8; ++i)
        acc[i & 3] = dot4(ld4(wr + base + (i << 8)), av[i], acc[i & 3]);
    float a = wave_sum((acc[0] + acc[1]) + (acc[2] + acc[3]));
    if (lane == 0) red_dot[w] = a;
    __syncthreads();
    if (tid == 0) {
        h[r0]     = x[r0]     + red_dot[0] + red_dot[1];
        h[r0 + 1] = x[r0 + 1] + red_dot[2] + red_dot[3];
    }
}

// ---------------------------------------------------------------------------
// k_gu: actt[r] = thr( silu(w1[r]·hn) * (w3[r]·hn) ), hn = thr(rmsnorm(h)*fnw)
// 1 row/wave, 4 rows/block. hn registerized (16 f4/lane); weight loop is a
// pure 32-load stream.
__global__ __launch_bounds__(256) void k_gu(const float* __restrict__ W1,
        const float* __restrict__ W3, const float* __restrict__ h,
        const float* __restrict__ fnw, float* __restrict__ actt) {
    const int lane = threadIdx.x & 63;
    const int r = (blockIdx.x << 2) + (threadIdx.x >> 6);
    const int base = lane << 2;

    f4 hv[16];
    float ss[4] = {0.f, 0.f, 0.f, 0.f};
#pragma unroll
    for (int i = 0; i < 16; ++i) {
        hv[i] = ld4(h + base + (i << 8));
        ss[i & 3] = dot4(hv[i], hv[i], ss[i & 3]);
    }
    float s = wave_sum((ss[0] + ss[1]) + (ss[2] + ss[3]));
    const float scale = rsqrtf(s * (1.f / (float)DIM) + EPS);
#pragma unroll
    for (int i = 0; i < 16; ++i)
        hv[i] = norm_thr(hv[i], ld4(fnw + base + (i << 8)), scale);

    const float* w1r = W1 + (size_t)r * DIM;
    const float* w3r = W3 + (size_t)r * DIM;
    float g[4] = {0.f, 0.f, 0.f, 0.f}, u[4] = {0.f, 0.f, 0.f, 0.f};
#pragma unroll
    for (int i = 0; i < 16; ++i) {
        f4 a = ld4(w1r + base + (i << 8));
        f4 b = ld4(w3r + base + (i << 8));
        g[i & 3] = dot4(a, hv[i], g[i & 3]);
        u[i & 3] = dot4(b, hv[i], u[i & 3]);
    }
    float gg = wave_sum((g[0] + g[1]) + (g[2] + g[3]));
    float uu = wave_sum((u[0] + u[1]) + (u[2] + u[3]));
    if (lane == 0) {
        float sg = gg / (1.f + expf(-gg));  // silu
        actt[r] = thr(sg * uu);
    }
}

// ---------------------------------------------------------------------------
// k_d: out[r] = h[r] + W2[r] · actt   (K = INTER = 43*256)
// 2 rows/block, row split across 2 waves by chunk parity (21/22 chunks each).
__global__ __launch_bounds__(256) void k_d(const float* __restrict__ W2,
        const float* __restrict__ actt, const float* __restrict__ h,
        float* __restrict__ out) {
    __shared__ float red_dot[4];
    const int tid = threadIdx.x;
    const int lane = tid & 63;
    const int w = tid >> 6;
    const int rowsel = w >> 1;
    const int parity = w & 1;
    const int r0 = blockIdx.x << 1;
    const int r = r0 + rowsel;
    const float* wr = W2 + (size_t)r * INTER + (parity << 8) + (lane << 2);
    const float* ar = actt + (parity << 8) + (lane << 2);

    float acc[4] = {0.f, 0.f, 0.f, 0.f};
#pragma unroll 7
    for (int i = 0; i < 21; ++i) {  // chunks parity, parity+2, ... (21 common)
        const int kk = i << 9;      // i*512 floats
        acc[i & 3] = dot4(ld4(wr + kk), ld4(ar + kk), acc[i & 3]);
    }
    if (parity == 0) {              // chunk 42 (only even-parity wave)
        const int kk = 42 << 8;
        f4 wv = ld4(W2 + (size_t)r * INTER + kk + (lane << 2));
        f4 av = ld4(actt + kk + (lane << 2));
        acc[1] = dot4(wv, av, acc[1]);
    }
    float a = wave_sum((acc[0] + acc[1]) + (acc[2] + acc[3]));
    if (lane == 0) red_dot[w] = a;
    __syncthreads();
    if (tid == 0) {
        out[r0]     = h[r0]     + red_dot[0] + red_dot[1];
        out[r0 + 1] = h[r0 + 1] + red_dot[2] + red_dot[3];
    }
}

extern "C" void kernel_launch(void* const* d_in, const int* in_sizes, int n_in,
                              void* d_out, int out_size, void* d_ws, size_t ws_size,
                              hipStream_t stream) {
    // setup_inputs order: x, freqs_cis, wqkv, wo, w1, w2, w3, attn_norm_w, ffn_norm_w, mask
    const float* x    = (const float*)d_in[0];
    const float* wqkv = (const float*)d_in[2];
    const float* wo   = (const float*)d_in[3];
    const float* w1   = (const float*)d_in[4];
    const float* w2   = (const float*)d_in[5];
    const float* w3   = (const float*)d_in[6];
    const float* anw  = (const float*)d_in[7];
    const float* fnw  = (const float*)d_in[8];
    float* out = (float*)d_out;

    float* ws   = (float*)d_ws;
    float* vt   = ws;            // 4096
    float* h    = ws + 4096;     // 4096
    float* actt = ws + 8192;     // 11008

    // V block of wqkv; Q/K rows are dead at SEQ=1 (softmax over 1 key == 1,
    // RoPE at pos 0 is identity).
    const float* wv = wqkv + (size_t)2 * 4096 * DIM;

    k_v <<<DIM / 2, 256, 0, stream>>>(wv, x, anw, vt);          // 2048 blocks
    k_o <<<DIM / 2, 256, 0, stream>>>(wo, vt, x, h);            // 2048 blocks
    k_gu<<<INTER / 4, 256, 0, stream>>>(w1, w3, h, fnw, actt);  // 2752 blocks
    k_d <<<DIM / 2, 256, 0, stream>>>(w2, actt, h, out);        // 2048 blocks
}